// Round 7
// baseline (424.013 us; speedup 1.0000x reference)
//
#include <hip/hip_runtime.h>
#include <math.h>
#include <stdint.h>

// Problem shape (fixed by setup_inputs): P=512, R=256, S=256, K=3, threshold=0.
#define Pn 512
#define Rn 256
#define Sn 256

typedef unsigned long long u64;
typedef unsigned int u32;

// ---- key machinery ----
__device__ __forceinline__ u32 mono(float f) {
  u32 u = __float_as_uint(f);
  return (u & 0x80000000u) ? ~u : (u | 0x80000000u);
}
__device__ __forceinline__ float unmono(u32 m) {
  u32 bits = (m & 0x80000000u) ? (m & 0x7FFFFFFFu) : ~m;
  return __uint_as_float(bits);
}
// u64 key: value-monotonic bits high, ~index low. Larger key = larger value;
// equal value -> smaller index wins (lax.top_k).
__device__ __forceinline__ u64 makekey(float v, int idx) {
  return ((u64)mono(v) << 32) | (u32)(~(u32)idx);
}
__device__ __forceinline__ void cswap(u64& a, u64& b) {
  const bool c = a > b;
  const u64 hi = c ? a : b;
  const u64 lo = c ? b : a;
  a = hi; b = lo;
}

// ---- branchless float top-3 insert (proven R5/R6). Strict >, ascending
// index insert order => smaller index wins ties = lax.top_k semantics. ----
__device__ __forceinline__ void ins3f(float v, int i,
    float& t0, int& i0, float& t1, int& i1, float& t2, int& i2) {
  const bool b0 = v > t0, b1 = v > t1, b2 = v > t2;
  const float nt0 = b0 ? v : t0;
  const int   ni0 = b0 ? i : i0;
  const float nt1 = b0 ? t0 : (b1 ? v : t1);
  const int   ni1 = b0 ? i0 : (b1 ? i : i1);
  const float nt2 = b1 ? t1 : (b2 ? v : t2);
  const int   ni2 = b1 ? i1 : (b2 ? i : i2);
  t0 = nt0; i0 = ni0; t1 = nt1; i1 = ni1; t2 = nt2; i2 = ni2;
}

// K1: col-slab partial top-3 (proven R5/R6). Block = (p, 64-row slab),
// thread-per-column, coalesced row loads. Single full HBM read of input.
__global__ __launch_bounds__(256) void colslab_kernel(
    const float* __restrict__ score,
    float* __restrict__ colpv, int* __restrict__ colpi) {
  const size_t PS = (size_t)Pn * Sn;
  const int p    = blockIdx.x >> 2;
  const int slab = blockIdx.x & 3;
  const int s    = threadIdx.x;
  const float* base = score + (size_t)p * Rn * Sn + (size_t)slab * 64 * Sn + s;
  float t0 = -INFINITY, t1 = -INFINITY, t2 = -INFINITY;
  int   i0 = -1, i1 = -1, i2 = -1;
  const int r0 = slab * 64;
  #pragma unroll 8
  for (int r = 0; r < 64; ++r)
    ins3f(base[(size_t)r * Sn], r0 + r, t0, i0, t1, i1, t2, i2);
  const size_t o = (size_t)p * Sn + s;
  colpv[(slab * 3 + 0) * PS + o] = t0; colpi[(slab * 3 + 0) * PS + o] = i0;
  colpv[(slab * 3 + 1) * PS + o] = t1; colpi[(slab * 3 + 1) * PS + o] = i1;
  colpv[(slab * 3 + 2) * PS + o] = t2; colpi[(slab * 3 + 2) * PS + o] = i2;
}

__device__ __forceinline__ void compute_elem(
    int s, int r, bool rmask, int sm,
    float rv0, float rv1, float rv2, int ri0, int ri1, int ri2,
    float a0, int b0, float a1, int b1, float a2, int b2,
    float& oscore, float& ocorr) {
  const float rv = (s == ri0) ? rv0 : (s == ri1) ? rv1 : (s == ri2) ? rv2 : 0.0f;
  const float sv = (r == b0) ? a0 : (r == b1) ? a1 : (r == b2) ? a2 : 0.0f;
  oscore = 0.5f * (rv + sv);
  const bool m = rmask && (sm != 0);
  ocorr = (((rv > 0.0f) || (sv > 0.0f)) && m) ? 1.0f : 0.0f;
}

// K2: per (p, 64-row slab) block. Merge col-slab partials in registers,
// then per row: re-read the row (L3-hot), wave top-3 via 32-bit mono-key
// butterfly (6 b32 shuffles/round) + ballot index recovery, compute, write.
// Tie-break exactness: equal values => equal mono keys; ballot's lowest set
// lane owns the smallest columns (columns increase with lane); within-lane
// ties already index-ordered by the u64 sort-4.
__global__ __launch_bounds__(256) void write_kernel(
    const float* __restrict__ score,
    const float* __restrict__ colpv, const int* __restrict__ colpi,
    const int* __restrict__ rmaskp, const int* __restrict__ smaskp,
    float* __restrict__ out) {
  const int p     = blockIdx.x >> 2;
  const int rbase = (blockIdx.x & 3) * 64;
  const int warp  = threadIdx.x >> 6;
  const int lane  = threadIdx.x & 63;
  const size_t PS = (size_t)Pn * Sn;
  const size_t N  = (size_t)Pn * Rn * Sn;
  const size_t cb = (size_t)p * Sn;

  // Merge 4 slab partials per column (ascending slab order, rank order).
  float4 T0 = reinterpret_cast<const float4*>(colpv + 0 * PS + cb)[lane];
  float4 T1 = reinterpret_cast<const float4*>(colpv + 1 * PS + cb)[lane];
  float4 T2 = reinterpret_cast<const float4*>(colpv + 2 * PS + cb)[lane];
  int4   I0 = reinterpret_cast<const int4*>(colpi + 0 * PS + cb)[lane];
  int4   I1 = reinterpret_cast<const int4*>(colpi + 1 * PS + cb)[lane];
  int4   I2 = reinterpret_cast<const int4*>(colpi + 2 * PS + cb)[lane];
  #pragma unroll
  for (int sk = 3; sk < 12; ++sk) {
    const float4 V = reinterpret_cast<const float4*>(colpv + (size_t)sk * PS + cb)[lane];
    const int4   I = reinterpret_cast<const int4*>(colpi + (size_t)sk * PS + cb)[lane];
    ins3f(V.x, I.x, T0.x, I0.x, T1.x, I1.x, T2.x, I2.x);
    ins3f(V.y, I.y, T0.y, I0.y, T1.y, I1.y, T2.y, I2.y);
    ins3f(V.z, I.z, T0.z, I0.z, T1.z, I1.z, T2.z, I2.z);
    ins3f(V.w, I.w, T0.w, I0.w, T1.w, I1.w, T2.w, I2.w);
  }
  T0.x = expf(T0.x); T0.y = expf(T0.y); T0.z = expf(T0.z); T0.w = expf(T0.w);
  T1.x = expf(T1.x); T1.y = expf(T1.y); T1.z = expf(T1.z); T1.w = expf(T1.w);
  T2.x = expf(T2.x); T2.y = expf(T2.y); T2.z = expf(T2.z); T2.w = expf(T2.w);

  const int4 sm = reinterpret_cast<const int4*>(smaskp + cb)[lane];
  const int sbase = lane * 4;
  const float* tile = score + (size_t)p * Rn * Sn;
  float* outp = out + (size_t)p * Rn * Sn;

  // Software pipeline: prefetch next row's float4 before processing current.
  float4 v = reinterpret_cast<const float4*>(tile + (size_t)(rbase + warp) * Sn)[lane];
  for (int it = 0; it < 16; ++it) {
    const int r = rbase + it * 4 + warp;
    float4 vn;
    if (it < 15)
      vn = reinterpret_cast<const float4*>(tile + (size_t)(r + 4) * Sn)[lane];

    // Per-lane sort-4 on u64 keys (exact within-lane tie order).
    const int b = lane * 4;
    u64 a0 = makekey(v.x, b + 0);
    u64 a1 = makekey(v.y, b + 1);
    u64 a2 = makekey(v.z, b + 2);
    u64 a3 = makekey(v.w, b + 3);
    cswap(a0, a1); cswap(a2, a3); cswap(a0, a2); cswap(a1, a3); cswap(a1, a2);
    u64 t0 = a0, t1 = a1, t2 = a2;

    float rv0, rv1, rv2;
    int   ri0, ri1, ri2;
    #pragma unroll
    for (int j = 0; j < 3; ++j) {
      u32 m = (u32)(t0 >> 32);
      #pragma unroll
      for (int off = 1; off < 64; off <<= 1) {
        const u32 o = __shfl_xor(m, off);
        m = (o > m) ? o : m;
      }
      const bool eq = ((u32)(t0 >> 32) == m);
      const u64 bal = __ballot(eq);
      const int owner = (int)__ffsll((unsigned long long)bal) - 1;
      const int idx = __shfl((int)(~(u32)t0), owner);
      const float val = expf(unmono(m));
      if (j == 0) { rv0 = val; ri0 = idx; }
      else if (j == 1) { rv1 = val; ri1 = idx; }
      else { rv2 = val; ri2 = idx; }
      const bool hit = eq && (lane == owner);
      t0 = hit ? t1 : t0;
      t1 = hit ? t2 : t1;
      t2 = hit ? 0ull : t2;
    }
    const bool rm = rmaskp[p * Rn + r] != 0;   // wave-uniform scalar load

    float4 osc, oco;
    compute_elem(sbase + 0, r, rm, sm.x, rv0, rv1, rv2, ri0, ri1, ri2,
                 T0.x, I0.x, T1.x, I1.x, T2.x, I2.x, osc.x, oco.x);
    compute_elem(sbase + 1, r, rm, sm.y, rv0, rv1, rv2, ri0, ri1, ri2,
                 T0.y, I0.y, T1.y, I1.y, T2.y, I2.y, osc.y, oco.y);
    compute_elem(sbase + 2, r, rm, sm.z, rv0, rv1, rv2, ri0, ri1, ri2,
                 T0.z, I0.z, T1.z, I1.z, T2.z, I2.z, osc.z, oco.z);
    compute_elem(sbase + 3, r, rm, sm.w, rv0, rv1, rv2, ri0, ri1, ri2,
                 T0.w, I0.w, T1.w, I1.w, T2.w, I2.w, osc.w, oco.w);

    reinterpret_cast<float4*>(outp + (size_t)r * Sn)[lane]     = osc;
    reinterpret_cast<float4*>(outp + N + (size_t)r * Sn)[lane] = oco;

    v = vn;
  }
}

extern "C" void kernel_launch(void* const* d_in, const int* in_sizes, int n_in,
                              void* d_out, int out_size, void* d_ws, size_t ws_size,
                              hipStream_t stream) {
  const float* score = (const float*)d_in[0];
  // d_in[1] = node_corr_scores: unused (conditional=False in reference)
  const int* rmask = (const int*)d_in[2];
  const int* smask = (const int*)d_in[3];
  float* out = (float*)d_out;

  const size_t PS = (size_t)Pn * Sn;
  // Workspace: col slab partials only (12 planes of values + indices).
  float* colpv = (float*)d_ws;              // 12*PS floats
  int*   colpi = (int*)(colpv + 12 * PS);   // 12*PS ints

  colslab_kernel<<<Pn * 4, 256, 0, stream>>>(score, colpv, colpi);
  write_kernel<<<Pn * 4, 256, 0, stream>>>(score, colpv, colpi,
                                           rmask, smask, out);
}